// Round 8
// baseline (125.900 us; speedup 1.0000x reference)
//
#include <hip/hip_runtime.h>
#include <stdint.h>

#define VOCAB 32000
#define KDIM  2048   // 2*HIDDEN
#define NDIM  1024   // HIDDEN
#define MTOK  16384  // 4*4096

typedef __bf16 bf16x8 __attribute__((ext_vector_type(8)));
typedef float  f32x4  __attribute__((ext_vector_type(4)));

__device__ __forceinline__ uint32_t pkbf(float a, float b) {
    union { __bf16 h[2]; uint32_t u; } r;
    r.h[0] = (__bf16)a; r.h[1] = (__bf16)b;
    return r.u;
}

__device__ __forceinline__ unsigned short f2bf(float f) {  // fallback path only
    union { float f; uint32_t u; } v; v.f = f;
    uint32_t u = v.u;
    return (unsigned short)((u + 0x7FFFu + ((u >> 16) & 1u)) >> 16);
}

__device__ __forceinline__ void gload_lds16(const void* g, void* l) {
    __builtin_amdgcn_global_load_lds(
        (const __attribute__((address_space(1))) uint32_t*)g,
        (__attribute__((address_space(3))) uint32_t*)l,
        16, 0, 0);
}

// ---------------------------------------------------------------------------
// One-time transpose+convert: W1 [K][N] f32 -> W1T [N][K] bf16
// ---------------------------------------------------------------------------
__global__ void w1_transpose_kernel(const float* __restrict__ W1,
                                    unsigned short* __restrict__ W1T) {
    __shared__ unsigned short tile[32][33];
    const int k0 = blockIdx.x * 32;
    const int n0 = blockIdx.y * 32;
    const int tx = threadIdx.x;
    const int ty = threadIdx.y;
#pragma unroll
    for (int i = 0; i < 4; ++i) {
        int kl = ty + i * 8;
        tile[kl][tx] = __builtin_bit_cast(unsigned short,
                            (__bf16)W1[(size_t)(k0 + kl) * NDIM + n0 + tx]);
    }
    __syncthreads();
#pragma unroll
    for (int i = 0; i < 4; ++i) {
        int nl = ty + i * 8;
        W1T[(size_t)(n0 + nl) * KDIM + k0 + tx] = tile[tx][nl];
    }
}

// ---------------------------------------------------------------------------
// m201-style 8-phase 256x256 fused gather-GEMM. BK=64, 2 K-tiles/iteration,
// 512 thr = 8 waves (WM=2 x WN=4). INTERLEAVED wave tiles: wave (wm,wn) owns
// A rows {mh*128 + wm*64 + mi*16} and B cols {nh*128 + wn*32 + nbi*16} for
// mh,nh in {0,1} -> phase quadrant (mh,nh) releases staging-half (mh|nh)
// early, enabling 3-6-phase-early staging with counted vmcnt (never drain).
// Phase = {stage-op; 12 ds_read b128; [vmcnt(6) ph3/ph7]; bar; setprio(1);
//          16 MFMA; setprio(0); bar}.
// Stage ledger (T=2i): ph0 dsW A1(T+1)[Q]; ph1 DMA B1(T+1); ph2 issue P<-
// A0(T+2); ph3 DMA B0(T+2)+VM6; ph4 dsW A0(T+2)[P], issue Q<-A1(T+2);
// ph5 issue P<-A0(T+3), DMA B1(T+2); ph6 dsW A1(T+2)[Q], issue Q<-A1(T+3);
// ph7 dsW A0(T+3)[P], DMA B0(T+3)+VM6.  (FIFO-verified: each vmcnt(6)
// retires the B half needed 1 phase later; ds_writes retire via the next
// phase's read auto-waits.)
// ---------------------------------------------------------------------------
__global__ __launch_bounds__(512, 2)
void emb_gemm_ws(const int* __restrict__ idx,
                 const float* __restrict__ W0,
                 const unsigned short* __restrict__ W1T,
                 float* __restrict__ out) {
    __shared__ __align__(16) char Abuf[2][2][128 * 128];  // [dbuf][half][128r x 128B]
    __shared__ __align__(16) char Bbuf[2][2][128 * 128];

    const int tid  = threadIdx.x;
    const int lane = tid & 63;
    const int wav  = tid >> 6;
    const int wm   = wav >> 2;      // 0..1
    const int wn   = wav & 3;       // 0..3
    const int m0   = blockIdx.x * 256;
    const int n0   = blockIdx.y * 256;

    const int rl = lane & 15;
    const int kg = (lane >> 4) * 16;

    // ---- A staging addressing: thread -> (row rA, fourth fA) of a half ----
    const int rA = tid >> 2;        // 0..127
    const int fA = tid & 3;
    const int awbyte = rA * 128 + fA * 32;
    const int swzA   = (rA & 7) << 4;
    uint32_t aoffH[2];
#pragma unroll
    for (int h = 0; h < 2; ++h)
        aoffH[h] = ((uint32_t)idx[m0 + h * 128 + rA] * KDIM + fA * 16) * 4u;

    // ---- B staging: 2 gloads/wave/half, pre-swizzled source chunks ----
    const int brin = lane >> 3;
    const int bch  = (lane & 7) ^ brin;
    uint32_t boffH[2][2];
    int bgrp[2];
#pragma unroll
    for (int j = 0; j < 2; ++j) {
        const int g = wav * 2 + j;          // 0..15 row-group of the half
        bgrp[j] = g * 1024;
#pragma unroll
        for (int h = 0; h < 2; ++h)
            boffH[h][j] = ((uint32_t)(n0 + h * 128 + g * 8 + brin) * KDIM + bch * 8) * 2u;
    }

    f32x4 P[4], Q[4];
    f32x4 acc[2][2][4][2] = {};   // [mh][nh][mi][nbi]

#define ISSUE_A(dst, h, t)                                               \
    _Pragma("unroll")                                                    \
    for (int j = 0; j < 4; ++j)                                          \
        dst[j] = *(const f32x4*)((const char*)W0 + aoffH[h] + (t) * 256 + j * 16);

#define WRITE_A(src, buf, hh)                                            \
    _Pragma("unroll")                                                    \
    for (int j = 0; j < 4; ++j) {                                        \
        uint2 pk_;                                                       \
        pk_.x = pkbf(src[j][0], src[j][1]);                              \
        pk_.y = pkbf(src[j][2], src[j][3]);                              \
        *(uint2*)(Abuf[buf][hh] + ((awbyte + j * 8) ^ swzA)) = pk_;      \
    }

#define DMA_B(buf, h, t)                                                 \
    _Pragma("unroll")                                                    \
    for (int j = 0; j < 2; ++j)                                          \
        gload_lds16((const char*)W1T + boffH[h][j] + (t) * 128,          \
                    Bbuf[buf][h] + bgrp[j]);

#define VM6 asm volatile("s_waitcnt vmcnt(6)" ::: "memory")
#define VM0 asm volatile("s_waitcnt vmcnt(0)" ::: "memory")
#define NOP (void)0

#define PHASE(buf, mh, nh, STAGE, FENCE)                                 \
    {                                                                    \
        STAGE;                                                           \
        bf16x8 A_[4][2], B_[2][2];                                       \
        _Pragma("unroll")                                                \
        for (int mi = 0; mi < 4; ++mi) {                                 \
            const int r_ = wm * 64 + mi * 16 + rl;                       \
            _Pragma("unroll")                                            \
            for (int ks = 0; ks < 2; ++ks)                               \
                A_[mi][ks] = *(const bf16x8*)(Abuf[buf][mh] +            \
                    ((r_ * 128 + ks * 64 + kg) ^ ((r_ & 7) << 4)));      \
        }                                                                \
        _Pragma("unroll")                                                \
        for (int nbi = 0; nbi < 2; ++nbi) {                              \
            const int c_ = wn * 32 + nbi * 16 + rl;                      \
            _Pragma("unroll")                                            \
            for (int ks = 0; ks < 2; ++ks)                               \
                B_[nbi][ks] = *(const bf16x8*)(Bbuf[buf][nh] +           \
                    ((c_ * 128 + ks * 64 + kg) ^ ((c_ & 7) << 4)));      \
        }                                                                \
        FENCE;                                                           \
        __builtin_amdgcn_s_barrier();                                    \
        __builtin_amdgcn_s_setprio(1);                                   \
        _Pragma("unroll")                                                \
        for (int ks = 0; ks < 2; ++ks)                                   \
            _Pragma("unroll")                                            \
            for (int mi = 0; mi < 4; ++mi)                               \
                _Pragma("unroll")                                        \
                for (int nbi = 0; nbi < 2; ++nbi)                        \
                    acc[mh][nh][mi][nbi] =                               \
                        __builtin_amdgcn_mfma_f32_16x16x32_bf16(         \
                            A_[mi][ks], B_[nbi][ks],                     \
                            acc[mh][nh][mi][nbi], 0, 0, 0);              \
        __builtin_amdgcn_s_setprio(0);                                   \
        __builtin_amdgcn_s_barrier();                                    \
    }

    // ---- prologue: buf0 <- tile0 full; buf1 <- A0,B0 of tile1; Q <- A1(t1)
    DMA_B(0, 0, 0); DMA_B(0, 1, 0); DMA_B(1, 0, 1);
    ISSUE_A(P, 0, 0); WRITE_A(P, 0, 0);
    ISSUE_A(P, 1, 0); WRITE_A(P, 0, 1);
    ISSUE_A(P, 0, 1); WRITE_A(P, 1, 0);
    ISSUE_A(Q, 1, 1);
    __syncthreads();   // one-time full drain

    // ---- main loop: 15 iterations x 2 K-tiles (tiles 0..29) ----
    for (int i = 0; i < 15; ++i) {
        const int T = 2 * i;
        PHASE(0, 0, 0, WRITE_A(Q, 1, 1),                        NOP)  // A1(T+1)
        PHASE(0, 0, 1, DMA_B(1, 1, T + 1),                      NOP)
        PHASE(0, 1, 0, ISSUE_A(P, 0, T + 2),                    NOP)
        PHASE(0, 1, 1, DMA_B(0, 0, T + 2),                      VM6)
        PHASE(1, 0, 0, WRITE_A(P, 0, 0); ISSUE_A(Q, 1, T + 2),  NOP)
        PHASE(1, 0, 1, ISSUE_A(P, 0, T + 3); DMA_B(0, 1, T + 2),NOP)
        PHASE(1, 1, 0, WRITE_A(Q, 0, 1); ISSUE_A(Q, 1, T + 3),  NOP)
        PHASE(1, 1, 1, WRITE_A(P, 1, 0); DMA_B(1, 0, T + 3),    VM6)
    }

    // ---- epilogue iteration: tiles 30 (buf0) and 31 (buf1) ----
    PHASE(0, 0, 0, WRITE_A(Q, 1, 1), NOP)   // A1(t31)
    PHASE(0, 0, 1, DMA_B(1, 1, 31),  NOP)
    PHASE(0, 1, 0, NOP,              NOP)
    PHASE(0, 1, 1, NOP,              VM0)
    PHASE(1, 0, 0, NOP,              NOP)
    PHASE(1, 0, 1, NOP,              NOP)
    PHASE(1, 1, 0, NOP,              NOP)
    PHASE(1, 1, 1, NOP,              NOP)

    // ---- output: mask (token==0) and scale by 32 = sqrt(1024) ----
    const int rowq = (lane >> 4) * 4;
#pragma unroll
    for (int mh = 0; mh < 2; ++mh)
#pragma unroll
    for (int mi = 0; mi < 4; ++mi)
#pragma unroll
    for (int rr = 0; rr < 4; ++rr) {
        const int m = m0 + mh * 128 + wm * 64 + mi * 16 + rowq + rr;
        const float msk = (idx[m] != 0) ? 32.0f : 0.0f;
#pragma unroll
        for (int nh = 0; nh < 2; ++nh)
#pragma unroll
        for (int nbi = 0; nbi < 2; ++nbi) {
            const int n = n0 + nh * 128 + wn * 32 + nbi * 16 + rl;
            out[(size_t)m * NDIM + n] = acc[mh][nh][mi][nbi][rr] * msk;
        }
    }
#undef ISSUE_A
#undef WRITE_A
#undef DMA_B
#undef PHASE
#undef VM6
#undef VM0
#undef NOP
}

// ---------------------------------------------------------------------------
// Fallback (ws too small): single-buffer, transpose-on-stage from W1 fp32.
// ---------------------------------------------------------------------------
__global__ __launch_bounds__(256)
void emb_gemm_nows(const int* __restrict__ idx,
                   const float* __restrict__ W0,
                   const float* __restrict__ W1,
                   float* __restrict__ out) {
    __shared__ __align__(16) char A_lds[128 * 128];
    __shared__ __align__(16) char B_lds[128 * 128];

    const int tid  = threadIdx.x;
    const int lane = tid & 63;
    const int wav  = tid >> 6;
    const int wm = wav >> 1;
    const int wn = wav & 1;
    const int m0 = blockIdx.x * 128;
    const int n0 = blockIdx.y * 128;

    const float* aSrc[8];
    int arow[8];
#pragma unroll
    for (int it = 0; it < 8; ++it) {
        int r = it * 16 + (tid >> 4);
        arow[it] = r;
        aSrc[it] = W0 + (size_t)idx[m0 + r] * KDIM;
    }
    const int acol4 = tid & 15;

    f32x4 acc[4][4] = {};

    for (int k0 = 0; k0 < KDIM; k0 += 64) {
#pragma unroll
        for (int it = 0; it < 8; ++it) {
            const int r = arow[it];
            const float4 v = *(const float4*)(aSrc[it] + k0 + acol4 * 4);
            uint2 pk;
            pk.x = pkbf(v.x, v.y);
            pk.y = pkbf(v.z, v.w);
            *(uint2*)(A_lds + ((r * 128 + acol4 * 8) ^ ((r & 7) << 4))) = pk;
        }
#pragma unroll
        for (int it = 0; it < 8; ++it) {
            const int k  = it * 8 + (tid >> 5);
            const int n4 = (tid & 31) * 4;
            const float4 v = *(const float4*)(W1 + (size_t)(k0 + k) * NDIM + n0 + n4);
            unsigned short h[4] = { f2bf(v.x), f2bf(v.y), f2bf(v.z), f2bf(v.w) };
#pragma unroll
            for (int i = 0; i < 4; ++i) {
                const int n = n4 + i;
                *(unsigned short*)(B_lds + ((n * 128 + k * 2) ^ ((n & 7) << 4))) = h[i];
            }
        }
        __syncthreads();

#pragma unroll
        for (int ks = 0; ks < 2; ++ks) {
            const int kb = ks * 64 + (lane >> 4) * 16;
            bf16x8 af[4], bfv[4];
#pragma unroll
            for (int mi = 0; mi < 4; ++mi) {
                const int r = wm * 64 + mi * 16 + (lane & 15);
                af[mi] = *(const bf16x8*)(A_lds + ((r * 128 + kb) ^ ((r & 7) << 4)));
            }
#pragma unroll
            for (int ni = 0; ni < 4; ++ni) {
                const int n = wn * 64 + ni * 16 + (lane & 15);
                bfv[ni] = *(const bf16x8*)(B_lds + ((n * 128 + kb) ^ ((n & 7) << 4)));
            }
#pragma unroll
            for (int mi = 0; mi < 4; ++mi)
#pragma unroll
                for (int ni = 0; ni < 4; ++ni)
                    acc[mi][ni] = __builtin_amdgcn_mfma_f32_16x16x32_bf16(
                        af[mi], bfv[ni], acc[mi][ni], 0, 0, 0);
        }
        __syncthreads();
    }

    const int col  = lane & 15;
    const int rowq = (lane >> 4) * 4;
#pragma unroll
    for (int mi = 0; mi < 4; ++mi) {
#pragma unroll
        for (int r = 0; r < 4; ++r) {
            const int m = m0 + wm * 64 + mi * 16 + rowq + r;
            const float msk = (idx[m] != 0) ? 32.0f : 0.0f;
#pragma unroll
            for (int ni = 0; ni < 4; ++ni) {
                const int n = n0 + wn * 64 + ni * 16 + col;
                out[(size_t)m * NDIM + n] = acc[mi][ni][r] * msk;
            }
        }
    }
}

extern "C" void kernel_launch(void* const* d_in, const int* in_sizes, int n_in,
                              void* d_out, int out_size, void* d_ws, size_t ws_size,
                              hipStream_t stream) {
    const int*   idx = (const int*)d_in[0];
    const float* W0  = (const float*)d_in[1];
    const float* W1  = (const float*)d_in[2];
    float*       out = (float*)d_out;

    const size_t w1t_bytes = (size_t)KDIM * NDIM * 2;

    if (ws_size >= w1t_bytes) {
        unsigned short* W1T = (unsigned short*)d_ws;
        dim3 tgrid(KDIM / 32, NDIM / 32);
        w1_transpose_kernel<<<tgrid, dim3(32, 8), 0, stream>>>(W1, W1T);
        dim3 grid(MTOK / 256, NDIM / 256);  // (64, 4) = 256 blocks = 1/CU
        emb_gemm_ws<<<grid, 512, 0, stream>>>(idx, W0, W1T, out);
    } else {
        dim3 grid(MTOK / 128, NDIM / 128);
        emb_gemm_nows<<<grid, 256, 0, stream>>>(idx, W0, W1, out);
    }
}

// Round 9
// 95.900 us; speedup vs baseline: 1.3128x; 1.3128x over previous
//
#include <hip/hip_runtime.h>
#include <stdint.h>

#define VOCAB 32000
#define KDIM  2048   // 2*HIDDEN
#define NDIM  1024   // HIDDEN
#define MTOK  16384  // 4*4096

typedef __bf16 bf16x8 __attribute__((ext_vector_type(8)));
typedef float  f32x4  __attribute__((ext_vector_type(4)));

__device__ __forceinline__ uint32_t pkbf(float a, float b) {
    union { __bf16 h[2]; uint32_t u; } r;
    r.h[0] = (__bf16)a; r.h[1] = (__bf16)b;
    return r.u;
}

__device__ __forceinline__ unsigned short f2bf(float f) {  // fallback path only
    union { float f; uint32_t u; } v; v.f = f;
    uint32_t u = v.u;
    return (unsigned short)((u + 0x7FFFu + ((u >> 16) & 1u)) >> 16);
}

// ---------------------------------------------------------------------------
// One-time transpose+convert: W1 [K][N] f32 -> W1T [N][K] bf16
// ---------------------------------------------------------------------------
__global__ void w1_transpose_kernel(const float* __restrict__ W1,
                                    unsigned short* __restrict__ W1T) {
    __shared__ unsigned short tile[32][33];
    const int k0 = blockIdx.x * 32;
    const int n0 = blockIdx.y * 32;
    const int tx = threadIdx.x;
    const int ty = threadIdx.y;
#pragma unroll
    for (int i = 0; i < 4; ++i) {
        int kl = ty + i * 8;
        tile[kl][tx] = __builtin_bit_cast(unsigned short,
                            (__bf16)W1[(size_t)(k0 + kl) * NDIM + n0 + tx]);
    }
    __syncthreads();
#pragma unroll
    for (int i = 0; i < 4; ++i) {
        int nl = ty + i * 8;
        W1T[(size_t)(n0 + nl) * KDIM + k0 + tx] = tile[tx][nl];
    }
}

// ---------------------------------------------------------------------------
// 256x256 fused gather-GEMM, R7 relaxed-barrier structure, with B taken OUT
// of LDS: W1T (4 MB) is L2-resident and every block reads it identically, so
// B fragments load straight from global into regs (16B/lane contiguous, the
// exact mfma_16x16x32 B-frag pattern). LDS holds only gathered A (64 KB
// dbuf). Per tile/CU this removes ~96 KB LDS reads + 32 KB DMA writes -> LDS
// pressure ~-45%. B(t+1) frags are issued right after the last use of the
// current ones (>= half-tile cover over ~200cy L2 latency). One
// __syncthreads per tile (A ds_write visibility + dbuf flip).
// 512 thr = 8 waves (2M x 4N), wave tile 128x64, acc[8][4] = 128 AGPR.
// XOR swizzle byte^=(r&7)<<4 on A (2-way alias = free).
// ---------------------------------------------------------------------------
__global__ __launch_bounds__(512, 2)
void emb_gemm_ws(const int* __restrict__ idx,
                 const float* __restrict__ W0,
                 const unsigned short* __restrict__ W1T,
                 float* __restrict__ out) {
    __shared__ __align__(16) char Abuf[2][256 * 128];  // 256 rows x 64 bf16

    const int tid  = threadIdx.x;   // 0..511
    const int lane = tid & 63;
    const int wav  = tid >> 6;      // 0..7
    const int wm   = wav >> 2;      // 0..1  (M half: 128 rows)
    const int wn   = wav & 3;       // 0..3  (N quarter: 64 cols)
    const int m0   = blockIdx.x * 256;
    const int n0   = blockIdx.y * 256;

    const int rl = lane & 15;
    const int kg = (lane >> 4) * 16;  // 16B k-subchunk within 64B half

    // ---- A gather setup: 8 chunks/thread (16B fp32 -> 8B bf16) ----
    const int ac = tid & 15;
    uint32_t aoff[8];
    int abyte[8];
#pragma unroll
    for (int it = 0; it < 8; ++it) {
        const int r = (tid >> 4) + it * 32;          // 0..255
        aoff[it]  = ((uint32_t)idx[m0 + r] * KDIM + ac * 4) * 4u;
        abyte[it] = (r * 128 + ac * 8) ^ ((r & 7) << 4);
    }

    // ---- B direct-global per-lane byte bases (frag layout = mem layout) ----
    uint32_t bcol[4];
#pragma unroll
    for (int ni = 0; ni < 4; ++ni)
        bcol[ni] = ((uint32_t)(n0 + wn * 64 + ni * 16 + rl) * KDIM) * 2u + kg;

    f32x4 apre[4];          // one A half-gather live at a time
    f32x4 acc[8][4] = {};   // [mh*4+mi][ni]
    bf16x8 bA[4], bB[4], af[4];

#define ISSUE_A_H(t, h)                                              \
    _Pragma("unroll")                                                \
    for (int j = 0; j < 4; ++j)                                      \
        apre[j] = *(const f32x4*)((const char*)W0 + aoff[(h) * 4 + j] + (t) * 256);

#define WRITE_A_H(buf, h)                                            \
    _Pragma("unroll")                                                \
    for (int j = 0; j < 4; ++j) {                                    \
        uint2 pk_;                                                   \
        pk_.x = pkbf(apre[j][0], apre[j][1]);                        \
        pk_.y = pkbf(apre[j][2], apre[j][3]);                        \
        *(uint2*)(Abuf[buf] + abyte[(h) * 4 + j]) = pk_;             \
    }

#define ISSUE_B(dst, t, ks)                                          \
    _Pragma("unroll")                                                \
    for (int ni = 0; ni < 4; ++ni)                                   \
        dst[ni] = *(const bf16x8*)((const char*)W1T + bcol[ni] +     \
                                   (t) * 128 + (ks) * 64);

#define READ_A(buf, ks, mh, dst)                                     \
    _Pragma("unroll")                                                \
    for (int mi = 0; mi < 4; ++mi) {                                 \
        const int r = wm * 128 + (mh) * 64 + mi * 16 + rl;           \
        dst[mi] = *(const bf16x8*)(Abuf[buf] +                       \
            ((r * 128 + (ks) * 64 + kg) ^ ((r & 7) << 4)));          \
    }

#define MFMA16(a_, b_, mh)                                           \
    __builtin_amdgcn_s_setprio(1);                                   \
    _Pragma("unroll")                                                \
    for (int mi = 0; mi < 4; ++mi)                                   \
        _Pragma("unroll")                                            \
        for (int ni = 0; ni < 4; ++ni)                               \
            acc[(mh) * 4 + mi][ni] =                                 \
                __builtin_amdgcn_mfma_f32_16x16x32_bf16(             \
                    a_[mi], b_[ni], acc[(mh) * 4 + mi][ni], 0, 0, 0);\
    __builtin_amdgcn_s_setprio(0);

    // ---- prologue: B(t0) into regs; gather+write A tile 0 into buf0 ----
    ISSUE_B(bA, 0, 0);
    ISSUE_B(bB, 0, 1);
    ISSUE_A_H(0, 0); WRITE_A_H(0, 0);
    ISSUE_A_H(0, 1); WRITE_A_H(0, 1);
    __syncthreads();

    // ---- main loop: 32 K-tiles, one barrier per tile ----
    for (int t = 0; t < 32; ++t) {
        const int cur = t & 1, nxt = cur ^ 1;
        const bool pf = (t < 31);

        if (pf) { ISSUE_A_H(t + 1, 0); }          // A(t+1) half 0 -> regs

        // ks = 0 (uses bA)
        READ_A(cur, 0, 0, af);
        MFMA16(af, bA, 0);
        READ_A(cur, 0, 1, af);
        MFMA16(af, bA, 1);

        if (pf) {
            ISSUE_B(bA, t + 1, 0);                // bA free: prefetch next ks0
            WRITE_A_H(nxt, 0);                    // apre h0 ~2 clusters old
            ISSUE_A_H(t + 1, 1);                  // A(t+1) half 1 -> regs
        }

        // ks = 1 (uses bB)
        READ_A(cur, 1, 0, af);
        MFMA16(af, bB, 0);
        READ_A(cur, 1, 1, af);
        MFMA16(af, bB, 1);

        if (pf) {
            ISSUE_B(bB, t + 1, 1);                // bB free: prefetch next ks1
            WRITE_A_H(nxt, 1);
        }
        __syncthreads();   // lgkm drain (A writes) + flip; vmcnt mostly aged
    }

    // ---- epilogue: mask (token==0) and scale by 32 = sqrt(1024) ----
    const int rowq = (lane >> 4) * 4;
#pragma unroll
    for (int mi = 0; mi < 8; ++mi) {
#pragma unroll
        for (int r = 0; r < 4; ++r) {
            const int m = m0 + wm * 128 + mi * 16 + rowq + r;
            const float msk = (idx[m] != 0) ? 32.0f : 0.0f;
#pragma unroll
            for (int ni = 0; ni < 4; ++ni) {
                const int n = n0 + wn * 64 + ni * 16 + rl;
                out[(size_t)m * NDIM + n] = acc[mi][ni][r] * msk;
            }
        }
    }
#undef ISSUE_A_H
#undef WRITE_A_H
#undef ISSUE_B
#undef READ_A
#undef MFMA16
}

// ---------------------------------------------------------------------------
// Fallback (ws too small): single-buffer, transpose-on-stage from W1 fp32.
// ---------------------------------------------------------------------------
__global__ __launch_bounds__(256)
void emb_gemm_nows(const int* __restrict__ idx,
                   const float* __restrict__ W0,
                   const float* __restrict__ W1,
                   float* __restrict__ out) {
    __shared__ __align__(16) char A_lds[128 * 128];
    __shared__ __align__(16) char B_lds[128 * 128];

    const int tid  = threadIdx.x;
    const int lane = tid & 63;
    const int wav  = tid >> 6;
    const int wm = wav >> 1;
    const int wn = wav & 1;
    const int m0 = blockIdx.x * 128;
    const int n0 = blockIdx.y * 128;

    const float* aSrc[8];
    int arow[8];
#pragma unroll
    for (int it = 0; it < 8; ++it) {
        int r = it * 16 + (tid >> 4);
        arow[it] = r;
        aSrc[it] = W0 + (size_t)idx[m0 + r] * KDIM;
    }
    const int acol4 = tid & 15;

    f32x4 acc[4][4] = {};

    for (int k0 = 0; k0 < KDIM; k0 += 64) {
#pragma unroll
        for (int it = 0; it < 8; ++it) {
            const int r = arow[it];
            const float4 v = *(const float4*)(aSrc[it] + k0 + acol4 * 4);
            uint2 pk;
            pk.x = pkbf(v.x, v.y);
            pk.y = pkbf(v.z, v.w);
            *(uint2*)(A_lds + ((r * 128 + acol4 * 8) ^ ((r & 7) << 4))) = pk;
        }
#pragma unroll
        for (int it = 0; it < 8; ++it) {
            const int k  = it * 8 + (tid >> 5);
            const int n4 = (tid & 31) * 4;
            const float4 v = *(const float4*)(W1 + (size_t)(k0 + k) * NDIM + n0 + n4);
            unsigned short h[4] = { f2bf(v.x), f2bf(v.y), f2bf(v.z), f2bf(v.w) };
#pragma unroll
            for (int i = 0; i < 4; ++i) {
                const int n = n4 + i;
                *(unsigned short*)(B_lds + ((n * 128 + k * 2) ^ ((n & 7) << 4))) = h[i];
            }
        }
        __syncthreads();

#pragma unroll
        for (int ks = 0; ks < 2; ++ks) {
            const int kb = ks * 64 + (lane >> 4) * 16;
            bf16x8 af[4], bfv[4];
#pragma unroll
            for (int mi = 0; mi < 4; ++mi) {
                const int r = wm * 64 + mi * 16 + (lane & 15);
                af[mi] = *(const bf16x8*)(A_lds + ((r * 128 + kb) ^ ((r & 7) << 4)));
            }
#pragma unroll
            for (int ni = 0; ni < 4; ++ni) {
                const int n = wn * 64 + ni * 16 + (lane & 15);
                bfv[ni] = *(const bf16x8*)(B_lds + ((n * 128 + kb) ^ ((n & 7) << 4)));
            }
#pragma unroll
            for (int mi = 0; mi < 4; ++mi)
#pragma unroll
                for (int ni = 0; ni < 4; ++ni)
                    acc[mi][ni] = __builtin_amdgcn_mfma_f32_16x16x32_bf16(
                        af[mi], bfv[ni], acc[mi][ni], 0, 0, 0);
        }
        __syncthreads();
    }

    const int col  = lane & 15;
    const int rowq = (lane >> 4) * 4;
#pragma unroll
    for (int mi = 0; mi < 4; ++mi) {
#pragma unroll
        for (int r = 0; r < 4; ++r) {
            const int m = m0 + wm * 64 + mi * 16 + rowq + r;
            const float msk = (idx[m] != 0) ? 32.0f : 0.0f;
#pragma unroll
            for (int ni = 0; ni < 4; ++ni) {
                const int n = n0 + wn * 64 + ni * 16 + col;
                out[(size_t)m * NDIM + n] = acc[mi][ni][r] * msk;
            }
        }
    }
}

extern "C" void kernel_launch(void* const* d_in, const int* in_sizes, int n_in,
                              void* d_out, int out_size, void* d_ws, size_t ws_size,
                              hipStream_t stream) {
    const int*   idx = (const int*)d_in[0];
    const float* W0  = (const float*)d_in[1];
    const float* W1  = (const float*)d_in[2];
    float*       out = (float*)d_out;

    const size_t w1t_bytes = (size_t)KDIM * NDIM * 2;

    if (ws_size >= w1t_bytes) {
        unsigned short* W1T = (unsigned short*)d_ws;
        dim3 tgrid(KDIM / 32, NDIM / 32);
        w1_transpose_kernel<<<tgrid, dim3(32, 8), 0, stream>>>(W1, W1T);
        dim3 grid(MTOK / 256, NDIM / 256);  // (64, 4) = 256 blocks = 1/CU
        emb_gemm_ws<<<grid, 512, 0, stream>>>(idx, W0, W1T, out);
    } else {
        dim3 grid(MTOK / 128, NDIM / 128);
        emb_gemm_nows<<<grid, 256, 0, stream>>>(idx, W0, W1, out);
    }
}

// Round 10
// 94.760 us; speedup vs baseline: 1.3286x; 1.0120x over previous
//
#include <hip/hip_runtime.h>
#include <stdint.h>

#define VOCAB 32000
#define KDIM  2048   // 2*HIDDEN
#define NDIM  1024   // HIDDEN
#define MTOK  16384  // 4*4096

typedef __bf16 bf16x8 __attribute__((ext_vector_type(8)));
typedef float  f32x4  __attribute__((ext_vector_type(4)));

__device__ __forceinline__ uint32_t pkbf(float a, float b) {
    union { __bf16 h[2]; uint32_t u; } r;
    r.h[0] = (__bf16)a; r.h[1] = (__bf16)b;
    return r.u;
}

__device__ __forceinline__ unsigned short f2bf(float f) {  // fallback path only
    union { float f; uint32_t u; } v; v.f = f;
    uint32_t u = v.u;
    return (unsigned short)((u + 0x7FFFu + ((u >> 16) & 1u)) >> 16);
}

// width-16 global->LDS DMA: per-lane global src, wave-uniform LDS base.
__device__ __forceinline__ void gload_lds16(const void* g, void* l) {
    __builtin_amdgcn_global_load_lds(
        (const __attribute__((address_space(1))) uint32_t*)g,
        (__attribute__((address_space(3))) uint32_t*)l,
        16, 0, 0);
}

// ---------------------------------------------------------------------------
// One-time transpose+convert: W1 [K][N] f32 -> W1T [N][K] bf16
// ---------------------------------------------------------------------------
__global__ void w1_transpose_kernel(const float* __restrict__ W1,
                                    unsigned short* __restrict__ W1T) {
    __shared__ unsigned short tile[32][33];
    const int k0 = blockIdx.x * 32;
    const int n0 = blockIdx.y * 32;
    const int tx = threadIdx.x;
    const int ty = threadIdx.y;
#pragma unroll
    for (int i = 0; i < 4; ++i) {
        int kl = ty + i * 8;
        tile[kl][tx] = __builtin_bit_cast(unsigned short,
                            (__bf16)W1[(size_t)(k0 + kl) * NDIM + n0 + tx]);
    }
    __syncthreads();
#pragma unroll
    for (int i = 0; i < 4; ++i) {
        int nl = ty + i * 8;
        W1T[(size_t)(n0 + nl) * KDIM + k0 + tx] = tile[tx][nl];
    }
}

// ---------------------------------------------------------------------------
// 256x256 fused gather-GEMM — R7 structure (best: 89.3us) with aged staging:
//   per tile t: 1) DMA B(t+1) into Bbuf[nxt] (free from tile start, dbuf)
//               2) issue all 8 A(t+1) gather loads -> apre
//               3) ks0: 2x {READ_A 4xb128; 16 MFMA}   (B frags from LDS)
//               4) WRITE_A all 8 chunks -> Abuf[nxt]  (vmcnt wait on apre
//                  ~1200cy aged; FIFO retirement also retires all B DMAs)
//               5) ks1: 2x {READ_A; 16 MFMA}          (~1300cy ages ds_writes)
//               6) __syncthreads                       (drain ~free now)
// No intra-tile barriers (all reads hit buf[cur]; all writes hit buf[nxt]).
// 512 thr = 8 waves (2M x 4N), wave tile 128x64, acc 128 AGPR. XOR swizzle
// byte^=(r&7)<<4 on both tiles (2-way alias = free); B staged via
// global_load_lds with pre-swizzled source chunks (rule 21).
// VGPR ledger: apre 32 + af 16 + bfv 16 + addr ~40 ~= 110 < 128 (no spill).
// ---------------------------------------------------------------------------
__global__ __launch_bounds__(512, 2)
void emb_gemm_ws(const int* __restrict__ idx,
                 const float* __restrict__ W0,
                 const unsigned short* __restrict__ W1T,
                 float* __restrict__ out) {
    __shared__ __align__(16) char Abuf[2][256 * 128];  // 256 rows x 64 bf16
    __shared__ __align__(16) char Bbuf[2][256 * 128];

    const int tid  = threadIdx.x;   // 0..511
    const int lane = tid & 63;
    const int wav  = tid >> 6;      // 0..7
    const int wm   = wav >> 2;      // 0..1  (M half: 128 rows)
    const int wn   = wav & 3;       // 0..3  (N quarter: 64 cols)
    const int m0   = blockIdx.x * 256;
    const int n0   = blockIdx.y * 256;

    const int rl = lane & 15;
    const int kg = (lane >> 4) * 16;  // 16B k-subchunk within 64B half

    // ---- A gather setup: 8 chunks/thread (16B fp32 -> 8B bf16) ----
    const int ac = tid & 15;
    uint32_t aoff[8];
    int abyte[8];
#pragma unroll
    for (int it = 0; it < 8; ++it) {
        const int r = (tid >> 4) + it * 32;          // 0..255
        aoff[it]  = ((uint32_t)idx[m0 + r] * KDIM + ac * 4) * 4u;
        abyte[it] = (r * 128 + ac * 8) ^ ((r & 7) << 4);
    }

    // ---- B staging: 4 gload_lds/wave (8 rows each), pre-swizzled source ----
    const int brin = lane >> 3;
    const int bch  = (lane & 7) ^ brin;
    uint32_t boff[4];
    int bbase[4];
#pragma unroll
    for (int i = 0; i < 4; ++i) {
        const int rg = wav * 32 + i * 8;  // wave-uniform 8-row group base
        boff[i]  = ((uint32_t)(n0 + rg + brin) * KDIM + bch * 8) * 2u;
        bbase[i] = rg * 128;
    }

    f32x4 apre[8];
    f32x4 acc[8][4] = {};   // [mh*4+mi][ni]
    bf16x8 af[4], bfv[4];

#define ISSUE_A8(t)                                                  \
    _Pragma("unroll")                                                \
    for (int j = 0; j < 8; ++j)                                      \
        apre[j] = *(const f32x4*)((const char*)W0 + aoff[j] + (t) * 256);

#define WRITE_A8(buf)                                                \
    _Pragma("unroll")                                                \
    for (int j = 0; j < 8; ++j) {                                    \
        uint2 pk_;                                                   \
        pk_.x = pkbf(apre[j][0], apre[j][1]);                        \
        pk_.y = pkbf(apre[j][2], apre[j][3]);                        \
        *(uint2*)(Abuf[buf] + abyte[j]) = pk_;                       \
    }

#define DMA_B(buf, t)                                                \
    _Pragma("unroll")                                                \
    for (int i = 0; i < 4; ++i)                                      \
        gload_lds16((const char*)W1T + boff[i] + (t) * 128,          \
                    Bbuf[buf] + bbase[i]);

#define READ_A(buf, ks, mh, dst)                                     \
    _Pragma("unroll")                                                \
    for (int mi = 0; mi < 4; ++mi) {                                 \
        const int r = wm * 128 + (mh) * 64 + mi * 16 + rl;           \
        dst[mi] = *(const bf16x8*)(Abuf[buf] +                       \
            ((r * 128 + (ks) * 64 + kg) ^ ((r & 7) << 4)));          \
    }

#define READ_B(buf, ks, dst)                                         \
    _Pragma("unroll")                                                \
    for (int ni = 0; ni < 4; ++ni) {                                 \
        const int n = wn * 64 + ni * 16 + rl;                        \
        dst[ni] = *(const bf16x8*)(Bbuf[buf] +                       \
            ((n * 128 + (ks) * 64 + kg) ^ ((n & 7) << 4)));          \
    }

#define MFMA16(a_, b_, mh)                                           \
    __builtin_amdgcn_s_setprio(1);                                   \
    _Pragma("unroll")                                                \
    for (int mi = 0; mi < 4; ++mi)                                   \
        _Pragma("unroll")                                            \
        for (int ni = 0; ni < 4; ++ni)                               \
            acc[(mh) * 4 + mi][ni] =                                 \
                __builtin_amdgcn_mfma_f32_16x16x32_bf16(             \
                    a_[mi], b_[ni], acc[(mh) * 4 + mi][ni], 0, 0, 0);\
    __builtin_amdgcn_s_setprio(0);

    // ---- prologue: stage K-tile 0 into buf0 ----
    DMA_B(0, 0);
    ISSUE_A8(0);
    WRITE_A8(0);       // vmcnt wait on apre subsumes B DMA (FIFO)
    __syncthreads();   // tile 0 visible

    // ---- main loop: 32 K-tiles, one (cheap) barrier per tile ----
    for (int t = 0; t < 32; ++t) {
        const int cur = t & 1, nxt = cur ^ 1;
        const bool pf = (t < 31);

        // 1+2) issue ALL next-tile loads up front (B first -> subsumed later)
        if (pf) { DMA_B(nxt, t + 1); ISSUE_A8(t + 1); }

        // 3) ks = 0
        READ_B(cur, 0, bfv);
        READ_A(cur, 0, 0, af);
        MFMA16(af, bfv, 0);
        READ_A(cur, 0, 1, af);
        MFMA16(af, bfv, 1);

        // 4) convert+write A(t+1): apre ~1200cy old; retiring it also
        //    retires every B DMA (issued earlier, FIFO vmcnt).
        if (pf) { WRITE_A8(nxt); }

        // 5) ks = 1 (~1300cy of MFMA ages the ds_writes)
        READ_B(cur, 1, bfv);
        READ_A(cur, 1, 0, af);
        MFMA16(af, bfv, 0);
        READ_A(cur, 1, 1, af);
        MFMA16(af, bfv, 1);

        // 6) boundary: everything old -> drain ~free
        __syncthreads();
    }

    // ---- epilogue: mask (token==0) and scale by 32 = sqrt(1024) ----
    const int rowq = (lane >> 4) * 4;
#pragma unroll
    for (int mi = 0; mi < 8; ++mi) {
#pragma unroll
        for (int r = 0; r < 4; ++r) {
            const int m = m0 + wm * 128 + mi * 16 + rowq + r;
            const float msk = (idx[m] != 0) ? 32.0f : 0.0f;
#pragma unroll
            for (int ni = 0; ni < 4; ++ni) {
                const int n = n0 + wn * 64 + ni * 16 + rl;
                out[(size_t)m * NDIM + n] = acc[mi][ni][r] * msk;
            }
        }
    }
#undef ISSUE_A8
#undef WRITE_A8
#undef DMA_B
#undef READ_A
#undef READ_B
#undef MFMA16
}

// ---------------------------------------------------------------------------
// Fallback (ws too small): single-buffer, transpose-on-stage from W1 fp32.
// ---------------------------------------------------------------------------
__global__ __launch_bounds__(256)
void emb_gemm_nows(const int* __restrict__ idx,
                   const float* __restrict__ W0,
                   const float* __restrict__ W1,
                   float* __restrict__ out) {
    __shared__ __align__(16) char A_lds[128 * 128];
    __shared__ __align__(16) char B_lds[128 * 128];

    const int tid  = threadIdx.x;
    const int lane = tid & 63;
    const int wav  = tid >> 6;
    const int wm = wav >> 1;
    const int wn = wav & 1;
    const int m0 = blockIdx.x * 128;
    const int n0 = blockIdx.y * 128;

    const float* aSrc[8];
    int arow[8];
#pragma unroll
    for (int it = 0; it < 8; ++it) {
        int r = it * 16 + (tid >> 4);
        arow[it] = r;
        aSrc[it] = W0 + (size_t)idx[m0 + r] * KDIM;
    }
    const int acol4 = tid & 15;

    f32x4 acc[4][4] = {};

    for (int k0 = 0; k0 < KDIM; k0 += 64) {
#pragma unroll
        for (int it = 0; it < 8; ++it) {
            const int r = arow[it];
            const float4 v = *(const float4*)(aSrc[it] + k0 + acol4 * 4);
            uint2 pk;
            pk.x = pkbf(v.x, v.y);
            pk.y = pkbf(v.z, v.w);
            *(uint2*)(A_lds + ((r * 128 + acol4 * 8) ^ ((r & 7) << 4))) = pk;
        }
#pragma unroll
        for (int it = 0; it < 8; ++it) {
            const int k  = it * 8 + (tid >> 5);
            const int n4 = (tid & 31) * 4;
            const float4 v = *(const float4*)(W1 + (size_t)(k0 + k) * NDIM + n0 + n4);
            unsigned short h[4] = { f2bf(v.x), f2bf(v.y), f2bf(v.z), f2bf(v.w) };
#pragma unroll
            for (int i = 0; i < 4; ++i) {
                const int n = n4 + i;
                *(unsigned short*)(B_lds + ((n * 128 + k * 2) ^ ((n & 7) << 4))) = h[i];
            }
        }
        __syncthreads();

#pragma unroll
        for (int ks = 0; ks < 2; ++ks) {
            const int kb = ks * 64 + (lane >> 4) * 16;
            bf16x8 af[4], bfv[4];
#pragma unroll
            for (int mi = 0; mi < 4; ++mi) {
                const int r = wm * 64 + mi * 16 + (lane & 15);
                af[mi] = *(const bf16x8*)(A_lds + ((r * 128 + kb) ^ ((r & 7) << 4)));
            }
#pragma unroll
            for (int ni = 0; ni < 4; ++ni) {
                const int n = wn * 64 + ni * 16 + (lane & 15);
                bfv[ni] = *(const bf16x8*)(B_lds + ((n * 128 + kb) ^ ((n & 7) << 4)));
            }
#pragma unroll
            for (int mi = 0; mi < 4; ++mi)
#pragma unroll
                for (int ni = 0; ni < 4; ++ni)
                    acc[mi][ni] = __builtin_amdgcn_mfma_f32_16x16x32_bf16(
                        af[mi], bfv[ni], acc[mi][ni], 0, 0, 0);
        }
        __syncthreads();
    }

    const int col  = lane & 15;
    const int rowq = (lane >> 4) * 4;
#pragma unroll
    for (int mi = 0; mi < 4; ++mi) {
#pragma unroll
        for (int r = 0; r < 4; ++r) {
            const int m = m0 + wm * 64 + mi * 16 + rowq + r;
            const float msk = (idx[m] != 0) ? 32.0f : 0.0f;
#pragma unroll
            for (int ni = 0; ni < 4; ++ni) {
                const int n = n0 + wn * 64 + ni * 16 + col;
                out[(size_t)m * NDIM + n] = acc[mi][ni][r] * msk;
            }
        }
    }
}

extern "C" void kernel_launch(void* const* d_in, const int* in_sizes, int n_in,
                              void* d_out, int out_size, void* d_ws, size_t ws_size,
                              hipStream_t stream) {
    const int*   idx = (const int*)d_in[0];
    const float* W0  = (const float*)d_in[1];
    const float* W1  = (const float*)d_in[2];
    float*       out = (float*)d_out;

    const size_t w1t_bytes = (size_t)KDIM * NDIM * 2;

    if (ws_size >= w1t_bytes) {
        unsigned short* W1T = (unsigned short*)d_ws;
        dim3 tgrid(KDIM / 32, NDIM / 32);
        w1_transpose_kernel<<<tgrid, dim3(32, 8), 0, stream>>>(W1, W1T);
        dim3 grid(MTOK / 256, NDIM / 256);  // (64, 4) = 256 blocks = 1/CU
        emb_gemm_ws<<<grid, 512, 0, stream>>>(idx, W0, W1T, out);
    } else {
        dim3 grid(MTOK / 128, NDIM / 128);
        emb_gemm_nows<<<grid, 256, 0, stream>>>(idx, W0, W1, out);
    }
}